// Round 1
// baseline (659.698 us; speedup 1.0000x reference)
//
#include <hip/hip_runtime.h>
#include <stdint.h>

#define EPS 1e-5f
#define DK 2048
#define DN 2048

typedef int i32x4 __attribute__((ext_vector_type(4)));

__device__ __forceinline__ void gload_lds16(const void* g, void* l) {
    __builtin_amdgcn_global_load_lds(
        (const __attribute__((address_space(1))) unsigned int*)g,
        (__attribute__((address_space(3))) unsigned int*)l,
        16, 0, 0);
}

// ---------------- kernel 1: sum(|W|) ----------------
__global__ void k_absum(const float4* __restrict__ w4, int n4, float* __restrict__ sum_out) {
    int tid = blockIdx.x * 256 + threadIdx.x;
    int stride = gridDim.x * 256;
    float s = 0.f;
    for (int i = tid; i < n4; i += stride) {
        float4 v = w4[i];
        s += fabsf(v.x) + fabsf(v.y) + fabsf(v.z) + fabsf(v.w);
    }
    #pragma unroll
    for (int off = 32; off; off >>= 1) s += __shfl_down(s, off, 64);
    __shared__ float lsum[4];
    if ((threadIdx.x & 63) == 0) lsum[threadIdx.x >> 6] = s;
    __syncthreads();
    if (threadIdx.x == 0)
        atomicAdd(sum_out, lsum[0] + lsum[1] + lsum[2] + lsum[3]);
}

// ---------------- kernel 2: ternary-quantize W ----------------
__global__ void k_quantw(const float4* __restrict__ w4, int* __restrict__ qw, int n4,
                         const float* __restrict__ sum_buf, float inv_n,
                         float* __restrict__ alpha_out) {
    float alpha = fmaxf(sum_buf[0] * inv_n, EPS);
    int tid = blockIdx.x * 256 + threadIdx.x;
    if (tid == 0) alpha_out[0] = alpha;
    int stride = gridDim.x * 256;
    for (int i = tid; i < n4; i += stride) {
        float4 v = w4[i];
        int a0 = min(1, max(-1, (int)rintf(v.x / alpha)));
        int a1 = min(1, max(-1, (int)rintf(v.y / alpha)));
        int a2 = min(1, max(-1, (int)rintf(v.z / alpha)));
        int a3 = min(1, max(-1, (int)rintf(v.w / alpha)));
        qw[i] = (a0 & 255) | ((a1 & 255) << 8) | ((a2 & 255) << 16) | ((a3 & 255) << 24);
    }
}

// ---------------- kernel 3: per-token absmax-quantize X ----------------
__device__ __forceinline__ int pack4(float4 v, float scale) {
    int a0 = min(127, max(-128, (int)rintf(v.x / scale)));
    int a1 = min(127, max(-128, (int)rintf(v.y / scale)));
    int a2 = min(127, max(-128, (int)rintf(v.z / scale)));
    int a3 = min(127, max(-128, (int)rintf(v.w / scale)));
    return (a0 & 255) | ((a1 & 255) << 8) | ((a2 & 255) << 16) | ((a3 & 255) << 24);
}

__global__ void k_quantx(const float* __restrict__ x, int* __restrict__ qx,
                         float* __restrict__ scales) {
    int token = blockIdx.x;
    const float4* row = (const float4*)(x + (size_t)token * DK);
    int tid = threadIdx.x;                       // 256 threads, 8 floats each
    float4 v0 = row[tid];
    float4 v1 = row[tid + 256];
    float m = fmaxf(fmaxf(fabsf(v0.x), fabsf(v0.y)), fmaxf(fabsf(v0.z), fabsf(v0.w)));
    m = fmaxf(m, fmaxf(fmaxf(fabsf(v1.x), fabsf(v1.y)), fmaxf(fabsf(v1.z), fabsf(v1.w))));
    #pragma unroll
    for (int off = 32; off; off >>= 1) m = fmaxf(m, __shfl_xor(m, off, 64));
    __shared__ float lm[4];
    if ((tid & 63) == 0) lm[tid >> 6] = m;
    __syncthreads();
    m = fmaxf(fmaxf(lm[0], lm[1]), fmaxf(lm[2], lm[3]));
    float scale = fmaxf(m, EPS) / 127.0f;
    if (tid == 0) scales[token] = scale;
    int* qrow = qx + (size_t)token * (DK / 4);
    qrow[tid]       = pack4(v0, scale);
    qrow[tid + 256] = pack4(v1, scale);
}

// ---------------- kernel 4: int8 GEMM, 128x128 tile, BK=128 ----------------
// A = qx [M][K] row-major, B = qw [N][K] row-major (i.e. B^T form).
// LDS: linear dest for global_load_lds; T2-style XOR swizzle realized by
// pre-swizzling the GLOBAL source column and applying the same XOR on ds_read.
__global__ __launch_bounds__(256) void k_gemm(
    const int8_t* __restrict__ qx, const int8_t* __restrict__ qw,
    const float* __restrict__ scales, const float* __restrict__ bias,
    const float* __restrict__ alphap, float* __restrict__ out) {

    __shared__ __align__(16) int8_t Als[128 * 128];   // 16 KB
    __shared__ __align__(16) int8_t Bls[128 * 128];   // 16 KB

    const int tid  = threadIdx.x;
    const int lane = tid & 63;
    const int wv   = tid >> 6;          // wave 0..3
    const int wm   = wv >> 1;           // 2x2 wave grid, 64x64 out each
    const int wn   = wv & 1;
    const int tn   = blockIdx.x & 15;   // N/128 = 16 (fastest: shares A-panel)
    const int tm   = blockIdx.x >> 4;

    i32x4 acc[4][4] = {};

    const int8_t* Ab = qx + (size_t)(tm * 128) * DK;
    const int8_t* Bb = qw + (size_t)(tn * 128) * DK;

    // staging: 16B unit u = (wv*4+i)*64 + lane; LDS row = u>>3, slot = u&7;
    // source column slot = slot ^ (row & 7)  (inverse of the read swizzle)
    int srow[4], scol[4];
    #pragma unroll
    for (int i = 0; i < 4; ++i) {
        int u = (wv * 4 + i) * 64 + lane;
        int r = u >> 3, s = u & 7;
        srow[i] = r;
        scol[i] = ((s ^ (r & 7)) << 4);
    }
    const int rsel = lane & 15;  // fragment row/col within 16
    const int ksel = lane >> 4;  // k-group 0..3 (16 bytes each)

    for (int kt = 0; kt < DK; kt += 128) {
        #pragma unroll
        for (int i = 0; i < 4; ++i) {
            gload_lds16(Ab + (size_t)srow[i] * DK + kt + scol[i], Als + (wv * 4 + i) * 1024);
            gload_lds16(Bb + (size_t)srow[i] * DK + kt + scol[i], Bls + (wv * 4 + i) * 1024);
        }
        __syncthreads();
        #pragma unroll
        for (int kk = 0; kk < 2; ++kk) {
            const int slot = kk * 4 + ksel;          // logical 16B slot in row
            i32x4 af[4], bf[4];
            #pragma unroll
            for (int f = 0; f < 4; ++f) {
                int ra = wm * 64 + f * 16 + rsel;
                af[f] = *(const i32x4*)(Als + ra * 128 + ((slot ^ (ra & 7)) << 4));
                int rb = wn * 64 + f * 16 + rsel;
                bf[f] = *(const i32x4*)(Bls + rb * 128 + ((slot ^ (rb & 7)) << 4));
            }
            #pragma unroll
            for (int fm = 0; fm < 4; ++fm)
                #pragma unroll
                for (int fn = 0; fn < 4; ++fn)
                    acc[fm][fn] = __builtin_amdgcn_mfma_i32_16x16x64_i8(
                        af[fm], bf[fn], acc[fm][fn], 0, 0, 0);
        }
        __syncthreads();
    }

    // epilogue: y = acc * (scale[row] * alpha) + bias[col]
    const float alpha = alphap[0];
    const int row0 = tm * 128 + wm * 64;
    const int col0 = tn * 128 + wn * 64;
    float sr[4][4];
    #pragma unroll
    for (int fm = 0; fm < 4; ++fm)
        #pragma unroll
        for (int j = 0; j < 4; ++j)
            sr[fm][j] = scales[row0 + fm * 16 + ksel * 4 + j] * alpha;
    float bc[4];
    #pragma unroll
    for (int fn = 0; fn < 4; ++fn) bc[fn] = bias[col0 + fn * 16 + rsel];
    #pragma unroll
    for (int fm = 0; fm < 4; ++fm)
        #pragma unroll
        for (int fn = 0; fn < 4; ++fn)
            #pragma unroll
            for (int j = 0; j < 4; ++j) {
                int r = row0 + fm * 16 + ksel * 4 + j;
                int c = col0 + fn * 16 + rsel;
                out[(size_t)r * DN + c] = (float)acc[fm][fn][j] * sr[fm][j] + bc[fn];
            }
}

// ---------------- launcher ----------------
extern "C" void kernel_launch(void* const* d_in, const int* in_sizes, int n_in,
                              void* d_out, int out_size, void* d_ws, size_t ws_size,
                              hipStream_t stream) {
    const float* x = (const float*)d_in[0];
    const float* w = (const float*)d_in[1];
    const float* b = (const float*)d_in[2];
    float* out = (float*)d_out;

    const int nw = in_sizes[1];           // 2048*2048
    const int M  = in_sizes[0] / DK;      // 32768

    uint8_t* ws = (uint8_t*)d_ws;
    int8_t* qx     = (int8_t*)ws;                                   // M*DK bytes
    int8_t* qw     = (int8_t*)(ws + (size_t)M * DK);                // nw bytes
    float*  scales = (float*)(ws + (size_t)M * DK + nw);            // M floats
    float*  sums   = (float*)(ws + (size_t)M * DK + nw + (size_t)M * 4); // [0]=sum,[1]=alpha

    hipMemsetAsync(sums, 0, 8, stream);
    k_absum<<<1024, 256, 0, stream>>>((const float4*)w, nw / 4, sums);
    k_quantw<<<1024, 256, 0, stream>>>((const float4*)w, (int*)qw, nw / 4,
                                       sums, 1.0f / (float)nw, sums + 1);
    k_quantx<<<M, 256, 0, stream>>>(x, (int*)qx, scales);
    k_gemm<<<(M / 128) * (DN / 128), 256, 0, stream>>>(qx, qw, scales, b, sums + 1, out);
}